// Round 7
// baseline (241.710 us; speedup 1.0000x reference)
//
#include <hip/hip_runtime.h>

// YOLO loss, forward only. pred/target: (16384, 7, 7, 30) fp32, out: scalar fp32.
// S=7, B=2, CLS=20, N=30, LAMBDA_COORD=5, LAMBDA_NOOBJ=0.5, BATCH=16384.
// NOTE: reference conf_loc = arange(B)*B+4 = [4,6] (not [4,9]) — mirrored here.
//
// R7: max-occupancy streaming sweep, no LDS scatter.
//   History: R1 (stride-120B loads) 75us TA-limited; R2 (ds_add atomics)
//   104us; R4/R5 regressions were SCRATCH SPILL (VGPR cap + full unroll),
//   not algorithm; R6 (spill-free LDS-scatter) 83us — 35 KB LDS caps
//   occupancy at 33%, 2 loads in flight -> MLP-starved (~21 KB in flight
//   vs ~15-22 KB needed per Little's law, at low duty cycle).
//   R7: keep only the 1 KB t4 gate table in LDS. 128-thread blocks,
//   launch_bounds(128,8) (VGPR<=64) -> up to 8 waves/SIMD. 1-deep software
//   prefetch in the sweep. Obj-cell IoU pass re-gathers from L2-warm global
//   (~15% of cells, ~7 MB) — the R4 "gather thrash" was actually spill.

#define TPB 128
#define NPER 30
#define CPB 256                     // cells per block (2 per thread)
#define TILE_FLOATS (CPB * NPER)    // 7680 floats per array per tile
#define R_TOTAL (16384 * 7 * 7)     // 802816 cells
#define NBLOCKS (R_TOTAL / CPB)     // 3136

__global__ __launch_bounds__(TPB, 8) void yolo_loss_kernel(
    const float* __restrict__ pred, const float* __restrict__ target,
    float* __restrict__ out)
{
    __shared__ float t4s[CPB];      // per-cell gate (t[...,4]), 1 KB
    __shared__ float red[TPB / 64];

    const int tid = threadIdx.x;
    const size_t tbase = (size_t)blockIdx.x * TILE_FLOATS;
    const float* gp = pred + tbase;
    const float* gt = target + tbase;

    // ---- Pre-pass: gather the 256 gates ----
    t4s[tid]       = gt[(size_t)tid * NPER + 4];
    t4s[tid + TPB] = gt[(size_t)(tid + TPB) * NPER + 4];
    __syncthreads();

    float acc_cls = 0.0f;   // sum over class slots, gated by (t4 == 1)
    float acc_no  = 0.0f;   // sum over conf_loc [4,6], gated by (t4 == 0)

    // ---- Sweep: coalesced float4 + 1-deep prefetch, register accumulation ----
    const float4* gp4 = (const float4*)gp;
    const float4* gt4 = (const float4*)gt;
    int F = tid;
    float4 vp = gp4[F];
    float4 vt = gt4[F];
    #pragma unroll 1
    for (int k = 0; k < TILE_FLOATS / (4 * TPB); k++) {   // 15 iterations
        float4 np = vp, nt = vt;
        if (k < TILE_FLOATS / (4 * TPB) - 1) {            // uniform branch
            np = gp4[F + TPB];
            nt = gt4[F + TPB];
        }

        unsigned f0 = 4u * (unsigned)F;            // first float index (even)
        unsigned c0 = (f0 * 34953u) >> 20;         // f0 / 30 (exact, f0 < 74898)
        int s0 = (int)(f0 - c0 * 30u);             // f0 % 30, even, 0..28
        float gA = t4s[c0];
        float gB = (s0 == 28) ? t4s[c0 + 1] : gA;  // wrap only when s0 == 28

        float pe[4] = {vp.x, vp.y, vp.z, vp.w};
        float te[4] = {vt.x, vt.y, vt.z, vt.w};
        #pragma unroll
        for (int i = 0; i < 4; i++) {
            int s = s0 + i;
            float g = gA;
            if (s >= 30) { s -= 30; g = gB; }
            float d = pe[i] - te[i];
            float q = d * d;
            acc_cls += ((s >= 10) && (g == 1.0f)) ? q : 0.0f;
            acc_no  += (((s == 4) | (s == 6)) && (g == 0.0f)) ? q : 0.0f;
        }

        vp = np; vt = nt; F += TPB;
    }

    // ---- Phase 2: obj cells only (exec-masked), L2-warm float2 gathers ----
    float acc_obj = 0.0f;
    #pragma unroll 1
    for (int cc = 0; cc < CPB / TPB; cc++) {
        int c = tid + cc * TPB;
        if (t4s[c] == 1.0f) {
            const float* p = gp + (size_t)c * NPER;
            const float* t = gt + (size_t)c * NPER;
            float2 p01 = *(const float2*)(p + 0);
            float2 p23 = *(const float2*)(p + 2);
            float2 p45 = *(const float2*)(p + 4);
            float2 p67 = *(const float2*)(p + 6);
            float2 p89 = *(const float2*)(p + 8);
            float2 t01 = *(const float2*)(t + 0);
            float2 t23 = *(const float2*)(t + 2);

            // target box -> xyxy (mirror reference float op order)
            float tx1 = t01.x - t23.x * 0.5f, ty1 = t01.y - t23.y * 0.5f;
            float tx2 = t01.x + t23.x * 0.5f, ty2 = t01.y + t23.y * 0.5f;
            float area2 = (tx2 - tx1) * (ty2 - ty1);

            // box 0: p[0..4]
            float ax1 = p01.x - p23.x * 0.5f, ay1 = p01.y - p23.y * 0.5f;
            float ax2 = p01.x + p23.x * 0.5f, ay2 = p01.y + p23.y * 0.5f;
            float w0 = fmaxf(fminf(ax2, tx2) - fmaxf(ax1, tx1), 0.0f);
            float h0 = fmaxf(fminf(ay2, ty2) - fmaxf(ay1, ty1), 0.0f);
            float inter0 = w0 * h0;
            float uni0 = (ax2 - ax1) * (ay2 - ay1) + area2 - inter0;
            float iou0 = (uni0 > 0.0f) ? (inter0 / uni0) : 0.0f;

            // box 1: p[5..9]
            float bx1 = p45.y - p67.y * 0.5f, by1 = p67.x - p89.x * 0.5f;
            float bx2 = p45.y + p67.y * 0.5f, by2 = p67.x + p89.x * 0.5f;
            float w1 = fmaxf(fminf(bx2, tx2) - fmaxf(bx1, tx1), 0.0f);
            float h1 = fmaxf(fminf(by2, ty2) - fmaxf(by1, ty1), 0.0f);
            float inter1 = w1 * h1;
            float uni1 = (bx2 - bx1) * (by2 - by1) + area2 - inter1;
            float iou1 = (uni1 > 0.0f) ? (inter1 / uni1) : 0.0f;

            // argmax over 2 -> first max index on ties
            bool j1 = (iou1 > iou0);
            float max_iou = fmaxf(iou0, iou1);
            float r0 = j1 ? p45.y : p01.x;   // x
            float r1 = j1 ? p67.x : p01.y;   // y
            float r2 = j1 ? p67.y : p23.x;   // w
            float r3 = j1 ? p89.x : p23.y;   // h
            float r4 = j1 ? p89.y : p45.x;   // conf

            float dx = r0 - t01.x;
            float dy = r1 - t01.y;
            float sw = sqrtf(fmaxf(r2, 0.0f)) - sqrtf(fmaxf(t23.x, 0.0f));
            float sh = sqrtf(fmaxf(r3, 0.0f)) - sqrtf(fmaxf(t23.y, 0.0f));
            float coord = dx * dx + dy * dy + sw * sw + sh * sh;
            float dc = r4 - max_iou;
            acc_obj += 5.0f * coord + dc * dc;
        }
    }

    float sum = acc_cls + 0.5f * acc_no + acc_obj;

    // wave-64 reduction -> per-block atomic
    #pragma unroll
    for (int off = 32; off > 0; off >>= 1)
        sum += __shfl_down(sum, off, 64);
    if ((tid & 63) == 0) red[tid >> 6] = sum;
    __syncthreads();
    if (tid == 0) {
        float s = red[0] + red[1];
        atomicAdd(out, s * (1.0f / 16384.0f));
    }
}

extern "C" void kernel_launch(void* const* d_in, const int* in_sizes, int n_in,
                              void* d_out, int out_size, void* d_ws, size_t ws_size,
                              hipStream_t stream) {
    const float* pred = (const float*)d_in[0];
    const float* target = (const float*)d_in[1];
    float* out = (float*)d_out;
    // d_out is poisoned with 0xAA before every launch; we accumulate into it.
    hipMemsetAsync(out, 0, sizeof(float), stream);
    yolo_loss_kernel<<<NBLOCKS, TPB, 0, stream>>>(pred, target, out);
}